// Round 6
// baseline (1289.338 us; speedup 1.0000x reference)
//
#include <hip/hip_runtime.h>

// Llama4TextExperts: E=8, H=2048, D=2048, 4096 tokens/expert.
// out = (up * silu(gate)) @ W2,  [gate|up] = x @ W1
// Round 6: 128x128 tile / BK=64 / 8 waves / 64 KiB LDS -> 2 blocks per CU
// (TLP covers vmcnt+barrier stalls that dominated at 1 block/CU). Counted
// lgkm waits; 2 barriers per K-tile; next-tile fragment reads moved after the
// vmcnt->barrier seal (also fixes r4's cross-wave staging race).

#define E_EXPERTS 8
#define TPE 4096
#define KD 2048

typedef __bf16 bf16_t;
typedef __bf16 bf16x4 __attribute__((ext_vector_type(4)));
typedef __bf16 bf16x8 __attribute__((ext_vector_type(8)));
typedef float f32x4 __attribute__((ext_vector_type(4)));

#define GLOAD16(src, dst)                                               \
  __builtin_amdgcn_global_load_lds(                                     \
      (const __attribute__((address_space(1))) void*)(src),             \
      (__attribute__((address_space(3))) void*)(dst), 16, 0, 0)

// ---------------- pass 1: x f32 -> bf16 ----------------
__global__ void cvt_f32_bf16_kernel(const float* __restrict__ in,
                                    bf16_t* __restrict__ out, long n4) {
  long i = (long)blockIdx.x * blockDim.x + threadIdx.x;
  const long stride = (long)gridDim.x * blockDim.x;
  const float4* in4 = (const float4*)in;
  bf16x4* out4 = (bf16x4*)out;
  for (; i < n4; i += stride) {
    float4 v = in4[i];
    bf16x4 o = {(bf16_t)v.x, (bf16_t)v.y, (bf16_t)v.z, (bf16_t)v.w};
    out4[i] = o;
  }
}

// ------- pass 2: per-expert transpose+convert: W[K][N] f32 -> WT[N][K] bf16 -------
__global__ void transpose_cvt_kernel(const float* __restrict__ W,
                                     bf16_t* __restrict__ WT, int K, int N) {
  __shared__ float tile[64][65];
  const int e = blockIdx.z;
  const float* Wp = W + (size_t)e * K * N;
  bf16_t* Tp = WT + (size_t)e * N * K;
  const int n0 = blockIdx.x * 64, k0 = blockIdx.y * 64;
  const int rr = threadIdx.x >> 4;
  const int cc = (threadIdx.x & 15) * 4;
#pragma unroll
  for (int p = 0; p < 4; ++p) {
    const int k = rr + p * 16;
    float4 v = *(const float4*)(Wp + (size_t)(k0 + k) * N + n0 + cc);
    tile[k][cc + 0] = v.x;
    tile[k][cc + 1] = v.y;
    tile[k][cc + 2] = v.z;
    tile[k][cc + 3] = v.w;
  }
  __syncthreads();
#pragma unroll
  for (int p = 0; p < 4; ++p) {
    const int n = rr + p * 16;
    bf16x4 o;
#pragma unroll
    for (int j = 0; j < 4; ++j) o[j] = (bf16_t)tile[cc + j][n];
    *(bf16x4*)(Tp + (size_t)(n0 + n) * K + k0 + cc) = o;
  }
}

// ---------------- 128x128 half-phase-pipelined grouped GEMM ----------------
// 8 waves, 2(M)x4(N) grid, 64x32 per wave. Per K-tile t (buf=t&1):
//  H1: read ALL frags (m01,b0,b1,m23 = 12 ds_read_b128); stageA(t+1,h0);
//      W6 -> m01,b0 ready; MFMA m01*b0.
//  H2: stageA(t+1,h1); W4 -> b1; MFMA m01*b1. BAR.
//  H3: stageB(t+2,h0); W0 -> m23; MFMA m23*b1.
//  H4: stageB(t+2,h1); MFMA m23*b0 (regs); VMC2; BAR.
// Race-safety (incl. cross-wave): tile t+1 LDS reads happen at t+1.H1, which
// is after every wave's t.H4 {VMC2 (drains A(t+1),B(t+1)) -> BAR}. stageA ->
// As[buf^1]: prior readers drained by t-1.{W6,W0} before t-1.H4 BAR. stageB
// (t+2)->Bs[buf]: b0/b1(t) readers drained by H1.W6/H2.W4, sealed by H2 BAR.
// VMC2 audit: outstanding at H4 = A(t+1)x2 + B(t+2)x2; keep newest 2 =
// B(t+2); everything older (incl. all of tile t+1) has landed.
template <bool FUSED, int NTN>
__global__ __launch_bounds__(512, 4) void moe_gemm128_kernel(
    const bf16_t* __restrict__ A, const bf16_t* __restrict__ Bm,
    void* __restrict__ Cout) {
  constexpr int NT = KD / 64;  // 32 K-tiles

  __shared__ alignas(16) bf16_t As[2][128][64];
  __shared__ alignas(16) bf16_t Bs[2][128][64];

  // XCD swizzle (grid%8==0): one expert per XCD; intra-XCD row-major
  // (consecutive blocks share the A-panel -> A stages L2-resident).
  const int NWG = gridDim.x;
  int wg = blockIdx.x;
  wg = (wg & 7) * (NWG >> 3) + (wg >> 3);
  const int per = 32 * NTN;
  const int e = wg / per;
  const int rem = wg % per;
  const int mt = rem / NTN, ntile = rem % NTN;
  const int t0 = mt * 128, n0 = ntile * 128;

  const int tid = threadIdx.x;
  const int wid = tid >> 6, lane = tid & 63;
  const int wr = wid >> 2, wc = wid & 3;  // 2(M) x 4(N); 64x32 per wave

  const bf16_t* Ae = A + (size_t)e * TPE * KD + (size_t)t0 * KD;
  const bf16_t* Be = Bm + (size_t)e * (size_t)(FUSED ? 4096 : 2048) * KD;

  const int slr = lane >> 3;               // row 0..7 in 8-row block
  const int sel = ((lane & 7) ^ slr) * 8;  // pre-swizzled source chunk

  // one gload per wave per half-tile (64 rows = 8 waves x 8 rows)
  auto stageA = [&](int kt, int h) {
    const int ktw = kt & (NT - 1);
    const int k0 = ktw * 64;
    const int buf = kt & 1;
    const int r0 = h * 64 + wid * 8;
    GLOAD16(Ae + (size_t)(r0 + slr) * KD + k0 + sel, &As[buf][r0][0]);
  };
  auto stageB = [&](int kt, int h) {
    const int ktw = kt & (NT - 1);
    const int k0 = ktw * 64;
    const int buf = kt & 1;
    const int r0 = h * 64 + wid * 8;
    const int R = n0 + r0 + slr;
    int srow;
    if constexpr (FUSED)
      srow = ((R >> 5) << 4) + (R & 15) + ((R >> 4) & 1) * 2048;
    else
      srow = R;
    GLOAD16(Be + (size_t)srow * KD + k0 + sel, &Bs[buf][r0][0]);
  };

  const int la = lane & 15, kg4 = lane >> 4;

  f32x4 acc[4][2] = {};          // [m-frag][n-frag]
  bf16x8 afP[2][2], afQ[2][2];   // m01 / m23  [mm][kk]
  bf16x8 bX[2], bY[2];           // b0 / b1    [kk]

  auto readAm = [&](int buf, int mp, bf16x8 (&dst)[2][2]) {
#pragma unroll
    for (int mm = 0; mm < 2; ++mm) {
      const int row = wr * 64 + mp * 32 + mm * 16 + la;
#pragma unroll
      for (int kk = 0; kk < 2; ++kk) {
        const int ch = ((kk * 4 + kg4) ^ (la & 7)) * 8;
        dst[mm][kk] = *(const bf16x8*)&As[buf][row][ch];
      }
    }
  };
  auto readBn = [&](int buf, int nf, bf16x8 (&dst)[2]) {
    const int row = wc * 32 + nf * 16 + la;
#pragma unroll
    for (int kk = 0; kk < 2; ++kk) {
      const int ch = ((kk * 4 + kg4) ^ (la & 7)) * 8;
      dst[kk] = *(const bf16x8*)&Bs[buf][row][ch];
    }
  };

#define W6 asm volatile("s_waitcnt lgkmcnt(6)" ::: "memory")
#define W4 asm volatile("s_waitcnt lgkmcnt(4)" ::: "memory")
#define W0 asm volatile("s_waitcnt lgkmcnt(0)" ::: "memory")
#define VMC2 asm volatile("s_waitcnt vmcnt(2)" ::: "memory")
#define BAR __builtin_amdgcn_s_barrier()
#define SCHED0 __builtin_amdgcn_sched_barrier(0)
#define PRIO1 __builtin_amdgcn_s_setprio(1)
#define PRIO0 __builtin_amdgcn_s_setprio(0)

  // 4 MFMA: m-pair MP (afP/afQ) x one n-frag NF x 2 kk
#define MMA_H(AF, NF, BF)                                                   \
  do {                                                                      \
    _Pragma("unroll") for (int kk = 0; kk < 2; ++kk) {                      \
      _Pragma("unroll") for (int mm = 0; mm < 2; ++mm) {                    \
        accp[mm][NF] = __builtin_amdgcn_mfma_f32_16x16x32_bf16(             \
            AF[mm][kk], BF[kk], accp[mm][NF], 0, 0, 0);                     \
      }                                                                     \
    }                                                                       \
  } while (0)

#define TILE(kt, buf)                                                       \
  do {                                                                      \
    /* H1: all fragment reads (12), issue order: m01(4),b0(2),b1(2),m23(4)*/\
    readAm(buf, 0, afP);                                                    \
    readBn(buf, 0, bX);                                                     \
    readBn(buf, 1, bY);                                                     \
    readAm(buf, 1, afQ);                                                    \
    stageA((kt) + 1, 0);                                                    \
    W6; SCHED0;                                                             \
    { auto& accp = accL;                                                    \
      PRIO1; MMA_H(afP, 0, bX); PRIO0;                                      \
      /* H2 */                                                              \
      stageA((kt) + 1, 1);                                                  \
      W4; SCHED0;                                                           \
      PRIO1; MMA_H(afP, 1, bY); PRIO0;                                      \
      BAR; }                                                                \
    /* H3 */                                                                \
    stageB((kt) + 2, 0);                                                    \
    W0; SCHED0;                                                             \
    { auto& accp = accH;                                                    \
      PRIO1; MMA_H(afQ, 1, bY); PRIO0;                                      \
      /* H4 */                                                              \
      stageB((kt) + 2, 1);                                                  \
      PRIO1; MMA_H(afQ, 0, bX); PRIO0; }                                    \
    VMC2;                                                                   \
    BAR;                                                                    \
  } while (0)

  auto accL = (f32x4(*)[2]) & acc[0];  // m01 rows
  auto accH = (f32x4(*)[2]) & acc[2];  // m23 rows

  // prologue: tile0 A+B, tile1 B; drain to 2 (tile1.B in flight)
  stageA(0, 0); stageA(0, 1);
  stageB(0, 0); stageB(0, 1);
  stageB(1, 0); stageB(1, 1);
  VMC2;
  BAR;

  for (int kt = 0; kt < NT; kt += 2) {
    TILE(kt, 0);
    TILE(kt + 1, 1);
  }

  // Epilogue. C/D layout: row=(lane>>4)*4+r, col=lane&15 (verified).
  const int lg = lane >> 4;
  const int rbase = t0 + wr * 64;
  if constexpr (FUSED) {
    bf16_t* Cp = (bf16_t*)Cout + (size_t)e * TPE * KD;
    const int jb = (n0 + wc * 32) >> 1;  // frag0=gate, frag1=up, same cols
#pragma unroll
    for (int m = 0; m < 4; ++m)
#pragma unroll
      for (int r = 0; r < 4; ++r) {
        const int row = rbase + m * 16 + lg * 4 + r;
        const int col = jb + la;
        const float g = acc[m][0][r], u = acc[m][1][r];
        const float s = 1.0f / (1.0f + __expf(-g));
        Cp[(size_t)row * KD + col] = (bf16_t)(u * g * s);
      }
  } else {
    float* Cp = (float*)Cout + (size_t)e * TPE * KD;
#pragma unroll
    for (int m = 0; m < 4; ++m)
#pragma unroll
      for (int n = 0; n < 2; ++n)
#pragma unroll
        for (int r = 0; r < 4; ++r) {
          const int row = rbase + m * 16 + lg * 4 + r;
          const int col = n0 + wc * 32 + n * 16 + la;
          Cp[(size_t)row * KD + col] = acc[m][n][r];
        }
  }
#undef W6
#undef W4
#undef W0
#undef VMC2
#undef BAR
#undef SCHED0
#undef PRIO1
#undef PRIO0
#undef MMA_H
#undef TILE
}

extern "C" void kernel_launch(void* const* d_in, const int* in_sizes, int n_in,
                              void* d_out, int out_size, void* d_ws,
                              size_t ws_size, hipStream_t stream) {
  const float* hs = (const float*)d_in[0];  // (32768, 2048)
  const float* w1 = (const float*)d_in[1];  // (8, 2048, 4096)
  const float* w2 = (const float*)d_in[2];  // (8, 2048, 2048)

  // ws layout (448 MiB):
  //   xb  bf16 [32768][2048]     128 MiB @ 0
  //   w1t bf16 [8][4096][2048]   128 MiB @ 128M
  //   w2t bf16 [8][2048][2048]    64 MiB @ 256M
  //   act bf16 [8][4096][2048]   128 MiB @ 320M
  char* ws = (char*)d_ws;
  bf16_t* xb = (bf16_t*)(ws);
  bf16_t* w1t = (bf16_t*)(ws + (size_t)134217728);
  bf16_t* w2t = (bf16_t*)(ws + (size_t)268435456);
  bf16_t* act = (bf16_t*)(ws + (size_t)335544320);

  const long n4 = (long)E_EXPERTS * TPE * KD / 4;
  cvt_f32_bf16_kernel<<<2048, 256, 0, stream>>>(hs, xb, n4);
  transpose_cvt_kernel<<<dim3(64, 32, 8), 256, 0, stream>>>(w1, w1t, 2048, 4096);
  transpose_cvt_kernel<<<dim3(32, 32, 8), 256, 0, stream>>>(w2, w2t, 2048, 2048);
  // G1: virtual N = 4096 (gate/up interleaved) -> NTN=32; 8*32*32 = 8192 wg
  moe_gemm128_kernel<true, 32><<<8192, 512, 0, stream>>>(xb, w1t, (void*)act);
  // G2: N = 2048 -> NTN=16; 8*32*16 = 4096 wg
  moe_gemm128_kernel<false, 16><<<4096, 512, 0, stream>>>(act, w2t, d_out);
}